// Round 5
// baseline (37.785 us; speedup 1.0000x reference)
//
#include <hip/hip_runtime.h>

#define B_SZ 512
#define V_SZ 1024
#define K_SZ 64
#define C_SZ 2048
#define A_SZ 128

#define LOG2E 1.4426950408889634f

__device__ __forceinline__ unsigned bf16_rne(float f) {
  unsigned u = __float_as_uint(f);
  return (u + 0x7FFFu + ((u >> 16) & 1u)) >> 16;   // round-nearest-even
}

// ---------------------------------------------------------------------------
// Kernel A: pack Wa/Wb/Wk (fp32 [1024][64]) into bf16 pairs:
//   wpk[m][v2*64+k] = bf16(W[2v2][k]) | bf16(W[2v2+1][k])<<16
// Halves GEMM read traffic; each 4B load feeds 2 FMAs.
// ---------------------------------------------------------------------------
__global__ __launch_bounds__(256) void gw_convW(
    const float* __restrict__ Wa, const float* __restrict__ Wb,
    const float* __restrict__ Wk, unsigned* __restrict__ wpk) {
  const int i = blockIdx.x * 256 + threadIdx.x;   // over 3*512*64 exactly
  const int m = i / (512 * K_SZ);
  const int r = i % (512 * K_SZ);
  const int v2 = r >> 6;
  const int k = r & 63;
  const float* __restrict__ W = (m == 0) ? Wa : (m == 1) ? Wb : Wk;
  const float w0 = W[(2 * v2) * K_SZ + k];        // 256B coalesced
  const float w1 = W[(2 * v2 + 1) * K_SZ + k];
  wpk[i] = bf16_rne(w0) | (bf16_rne(w1) << 16);
}

// ---------------------------------------------------------------------------
// Kernel B (fused): one block (512 thr) per batch row.
// Phase A: waves 0-5 compute the 3x64 dot products (each (mat, v-half) pair
//          owns 512 of the 1024 v's; packed-bf16 W loads, LDS reduce).
//          alpha/beta/kappa stay in LDS; only new_kappa is written out.
// Phase B: conservative cutoff CL (term <= 2^-150 beyond), phi -> LDS+global,
//          exact zeros beyond CL, window = phi[0:CL) @ text[0:CL).
// ---------------------------------------------------------------------------
__global__ __launch_bounds__(512) void gw_fused(
    const float* __restrict__ x, const float* __restrict__ text,
    const float* __restrict__ prev_kappa, const unsigned* __restrict__ wpk,
    const float* __restrict__ ba, const float* __restrict__ bb,
    const float* __restrict__ bk,
    float* __restrict__ out_phi, float* __restrict__ out_kappa,
    float* __restrict__ out_window) {
  __shared__ float xs[V_SZ];
  __shared__ float part[6][K_SZ];
  __shared__ float al[K_SZ];
  __shared__ float bn[K_SZ];     // -log2(e) * beta
  __shared__ float kap[K_SZ];
  __shared__ float bnd[K_SZ];
  __shared__ int cl_s;
  __shared__ float phi_s[C_SZ];
  __shared__ float4 red[16][32];

  const int tid = threadIdx.x;
  const int b = blockIdx.x;

  // stage x row (256 float4 = 4KB)
  if (tid < 256) {
    ((float4*)xs)[tid] = ((const float4*)(x + (size_t)b * V_SZ))[tid];
  }
  __syncthreads();

  const int which = tid >> 6;
  const int k = tid & 63;

  // ---- Phase A: GEMM (waves 0-5) ----
  if (which < 6) {
    const int m = which >> 1;        // 0=alpha, 1=beta, 2=kappa
    const int half = which & 1;
    const unsigned* __restrict__ Wp = wpk + m * (512 * K_SZ);
    const int v2b = half * 256;
    float acc0 = 0.f, acc1 = 0.f;
#pragma unroll 8
    for (int v2 = v2b; v2 < v2b + 256; ++v2) {
      unsigned w2 = Wp[v2 * K_SZ + k];               // 256B coalesced
      float w0 = __uint_as_float(w2 << 16);          // low bf16
      float w1 = __uint_as_float(w2 & 0xFFFF0000u);  // high bf16
      acc0 = fmaf(xs[2 * v2],     w0, acc0);         // LDS broadcast
      acc1 = fmaf(xs[2 * v2 + 1], w1, acc1);
    }
    part[which][k] = acc0 + acc1;
  }
  __syncthreads();

  if (tid < 192) {
    const int m = which;             // 0,1,2
    float s = part[2 * m][k] + part[2 * m + 1][k];
    const float bias = ((m == 0) ? ba : (m == 1) ? bb : bk)[k];
    const float e = expf(s + bias);
    if (m == 0) {
      al[k] = e;
    } else if (m == 1) {
      bn[k] = -LOG2E * e;
    } else {
      float nk = prev_kappa[b * K_SZ + k] + e;
      kap[k] = nk;
      out_kappa[b * K_SZ + k] = nk;
    }
  }
  __syncthreads();

  // ---- cutoff: term <= 2^-150 for c >= bnd  (LOG2E*beta == -bn) ----
  if (tid < K_SZ) {
    float num = 150.f + fmaxf(0.f, log2f(al[tid]));
    bnd[tid] = kap[tid] + sqrtf(num / (-bn[tid]));
  }
  __syncthreads();
  if (tid == 0) {
    float m = 0.f;
    for (int i = 0; i < K_SZ; ++i) m = fmaxf(m, bnd[i]);
    m = fminf(m, (float)C_SZ);       // sanitizes inf -> full compute
    int cl = (int)m + 1;
    cl = (cl + 15) & ~15;            // multiple of 16 for the window loop
    if (cl > C_SZ) cl = C_SZ;
    cl_s = cl;
  }
  __syncthreads();
  const int CL = cl_s;

  // ---- phi for c < CL ----
  for (int c = tid; c < CL; c += 512) {
    float cf = (float)c;
    float s = 0.f;
#pragma unroll
    for (int kk = 0; kk < K_SZ; ++kk) {
      float d = kap[kk] - cf;
      s += al[kk] * exp2f(bn[kk] * d * d);
    }
    phi_s[c] = s;
    out_phi[(size_t)b * C_SZ + c] = s;
  }
  // ---- exact zeros for c >= CL ----
  {
    float4 z = make_float4(0.f, 0.f, 0.f, 0.f);
    float4* po = (float4*)(out_phi + (size_t)b * C_SZ);
    for (int i = (CL >> 2) + tid; i < C_SZ / 4; i += 512) po[i] = z;
  }
  __syncthreads();

  // ---- window over [0, CL) rows of text ----
  const float4* __restrict__ t4 =
      (const float4*)(text + (size_t)b * C_SZ * A_SZ);
  const int a4 = tid & 31;   // float4 column (covers A=128)
  const int cr = tid >> 5;   // 16 parallel c-rows

  float4 acc = make_float4(0.f, 0.f, 0.f, 0.f);
  for (int cc = cr; cc < CL; cc += 16) {
    float p = phi_s[cc];
    float4 t = t4[cc * 32 + a4];     // coalesced 512B per row
    acc.x = fmaf(p, t.x, acc.x);
    acc.y = fmaf(p, t.y, acc.y);
    acc.z = fmaf(p, t.z, acc.z);
    acc.w = fmaf(p, t.w, acc.w);
  }

  red[cr][a4] = acc;
  __syncthreads();

  if (tid < 32) {
    float4 w = red[0][tid];
#pragma unroll
    for (int i = 1; i < 16; ++i) {
      float4 r = red[i][tid];
      w.x += r.x; w.y += r.y; w.z += r.z; w.w += r.w;
    }
    ((float4*)(out_window + (size_t)b * A_SZ))[tid] = w;
  }
}

extern "C" void kernel_launch(void* const* d_in, const int* in_sizes, int n_in,
                              void* d_out, int out_size, void* d_ws, size_t ws_size,
                              hipStream_t stream) {
  const float* x    = (const float*)d_in[0];
  const float* text = (const float*)d_in[1];
  const float* pk   = (const float*)d_in[2];
  const float* Wa   = (const float*)d_in[3];
  const float* ba   = (const float*)d_in[4];
  const float* Wb   = (const float*)d_in[5];
  const float* bb   = (const float*)d_in[6];
  const float* Wk   = (const float*)d_in[7];
  const float* bk   = (const float*)d_in[8];

  float* out        = (float*)d_out;
  float* out_phi    = out;                              // B*C
  float* out_kappa  = out + (size_t)B_SZ * C_SZ;        // B*K
  float* out_win    = out_kappa + (size_t)B_SZ * K_SZ;  // B*A

  unsigned* wpk     = (unsigned*)d_ws;                  // 3*512*64*4 = 393KB

  gw_convW<<<(3 * 512 * K_SZ) / 256, 256, 0, stream>>>(Wa, Wb, Wk, wpk);
  gw_fused<<<B_SZ, 512, 0, stream>>>(x, text, pk, wpk, ba, bb, bk,
                                     out_phi, out_kappa, out_win);
}

// Round 6
// 22.898 us; speedup vs baseline: 1.6502x; 1.6502x over previous
//
#include <hip/hip_runtime.h>

#define B_SZ 512
#define V_SZ 1024
#define K_SZ 64
#define C_SZ 2048
#define A_SZ 128

#define LOG2E 1.4426950408889634f

// ---------------------------------------------------------------------------
// Kernel 1: alpha = exp(xs@Wa+ba), beta = exp(xs@Wb+bb),
//           new_kappa = prev_kappa + exp(xs@Wk+bk)
// 256 blocks x 768 threads (12 waves), 2 batch rows per block.
// Wave w: matrix m = w>>2, v-quarter q = w&3, lane = k. ONE W-stream per
// wave (1 global load/iter), x-rows interleaved in LDS as float2
// (1 ds_read_b64/iter), 2 FMAs. L2 W-traffic halves vs 1-row blocks:
// 256 x 786KB = 201MB ~= 5.9us floor; 3 waves/SIMD for latency hiding.
// ---------------------------------------------------------------------------
__global__ __launch_bounds__(768) void gw_abk(
    const float* __restrict__ x,
    const float* __restrict__ prev_kappa,
    const float* __restrict__ Wa, const float* __restrict__ ba,
    const float* __restrict__ Wb, const float* __restrict__ bb,
    const float* __restrict__ Wk, const float* __restrict__ bk,
    float* __restrict__ ws_alpha, float* __restrict__ ws_beta,
    float* __restrict__ ws_kappa, float* __restrict__ out_kappa) {
  __shared__ float2 xs2[V_SZ];            // 8KB: {row0[v], row1[v]}
  __shared__ float part[12][2][K_SZ];     // 6KB: [wave][row][k]

  const int tid = threadIdx.x;
  const int b0 = blockIdx.x * 2;

  {
    const float* x0 = x + (size_t)b0 * V_SZ;
    const float* x1 = x0 + V_SZ;
    for (int i = tid; i < V_SZ; i += 768)
      xs2[i] = make_float2(x0[i], x1[i]);   // coalesced sweeps
  }
  __syncthreads();

  const int w = tid >> 6;     // wave 0..11
  const int m = w >> 2;       // 0=alpha, 1=beta, 2=kappa
  const int q = w & 3;        // v-quarter
  const int k = tid & 63;
  const float* __restrict__ Wm = (m == 0) ? Wa : (m == 1) ? Wb : Wk;

  float acc0 = 0.f, acc1 = 0.f;
  const int v0 = q * 256;
#pragma unroll 16
  for (int v = v0; v < v0 + 256; ++v) {
    float wv = Wm[v * K_SZ + k];    // 256B coalesced, single stream
    float2 xv = xs2[v];             // one ds_read_b64, wave-uniform addr
    acc0 = fmaf(xv.x, wv, acc0);
    acc1 = fmaf(xv.y, wv, acc1);
  }
  part[w][0][k] = acc0;
  part[w][1][k] = acc1;
  __syncthreads();

  // 384 work items: m = tid>>7, r = (tid>>6)&1, kk = tid&63
  if (tid < 384) {
    const int mm = tid >> 7;
    const int r = (tid >> 6) & 1;
    const int kk = tid & 63;
    float s = part[mm * 4 + 0][r][kk] + part[mm * 4 + 1][r][kk] +
              part[mm * 4 + 2][r][kk] + part[mm * 4 + 3][r][kk];
    const float bias = ((mm == 0) ? ba : (mm == 1) ? bb : bk)[kk];
    const float e = expf(s + bias);
    const int idx = (b0 + r) * K_SZ + kk;
    if (mm == 0) {
      ws_alpha[idx] = e;
    } else if (mm == 1) {
      ws_beta[idx] = e;
    } else {
      float nk = prev_kappa[idx] + e;
      ws_kappa[idx] = nk;
      out_kappa[idx] = nk;
    }
  }
}

// ---------------------------------------------------------------------------
// Kernel 2 (verbatim from passing R4): one block (512 threads) per batch row.
//  1) conservative cutoff CL: for c >= CL every Gaussian term <= 2^-150
//     -> phi[c] == 0 exactly (vs absmax threshold ~6.9).
//  2) phi[c] for c < CL (exact), zeros beyond; write phi output.
//  3) window = phi[0:CL) @ text[0:CL)  -- reads only CL rows of text.
// ---------------------------------------------------------------------------
__global__ __launch_bounds__(512) void gw_phi_window(
    const float* __restrict__ text,
    const float* __restrict__ ws_alpha, const float* __restrict__ ws_beta,
    const float* __restrict__ ws_kappa,
    float* __restrict__ out_phi, float* __restrict__ out_window) {
  __shared__ float al[K_SZ];
  __shared__ float bn[K_SZ];     // -log2(e) * beta  (exp2 scale)
  __shared__ float kap[K_SZ];
  __shared__ float bnd[K_SZ];
  __shared__ int cl_s;
  __shared__ float phi_s[C_SZ];
  __shared__ float4 red[16][32];

  const int tid = threadIdx.x;
  const int b = blockIdx.x;

  if (tid < K_SZ) {
    float a  = ws_alpha[b * K_SZ + tid];
    float be = ws_beta[b * K_SZ + tid];
    float kp = ws_kappa[b * K_SZ + tid];
    al[tid] = a;
    bn[tid] = -LOG2E * be;
    kap[tid] = kp;
    // solve LOG2E*be*d^2 >= 150 + max(0, log2(a))  ->  term <= 2^-150
    float num = 150.f + fmaxf(0.f, log2f(a));
    bnd[tid] = kp + sqrtf(num / (LOG2E * be));
  }
  __syncthreads();

  if (tid == 0) {
    float m = 0.f;
    for (int i = 0; i < K_SZ; ++i) m = fmaxf(m, bnd[i]);
    m = fminf(m, (float)C_SZ);        // also sanitizes inf -> full compute
    int cl = (int)m + 1;
    cl = (cl + 15) & ~15;             // multiple of 16 for the window loop
    if (cl > C_SZ) cl = C_SZ;
    cl_s = cl;
  }
  __syncthreads();
  const int CL = cl_s;

  // ---- phi for c < CL ----
  for (int c = tid; c < CL; c += 512) {
    float cf = (float)c;
    float s = 0.f;
#pragma unroll
    for (int k = 0; k < K_SZ; ++k) {
      float d = kap[k] - cf;
      s += al[k] * exp2f(bn[k] * d * d);
    }
    phi_s[c] = s;
    out_phi[(size_t)b * C_SZ + c] = s;
  }
  // ---- exact zeros for c >= CL ----
  {
    float4 z = make_float4(0.f, 0.f, 0.f, 0.f);
    float4* po = (float4*)(out_phi + (size_t)b * C_SZ);
    for (int i = (CL >> 2) + tid; i < C_SZ / 4; i += 512) po[i] = z;
  }
  __syncthreads();

  // ---- window over [0, CL) rows of text ----
  const float4* __restrict__ t4 =
      (const float4*)(text + (size_t)b * C_SZ * A_SZ);
  const int a4 = tid & 31;   // float4 column (covers A=128)
  const int cr = tid >> 5;   // 16 parallel c-rows

  float4 acc = make_float4(0.f, 0.f, 0.f, 0.f);
  for (int cc = cr; cc < CL; cc += 16) {
    float p = phi_s[cc];
    float4 t = t4[cc * 32 + a4];       // coalesced 512B per row
    acc.x = fmaf(p, t.x, acc.x);
    acc.y = fmaf(p, t.y, acc.y);
    acc.z = fmaf(p, t.z, acc.z);
    acc.w = fmaf(p, t.w, acc.w);
  }

  red[cr][a4] = acc;
  __syncthreads();

  if (tid < 32) {
    float4 w = red[0][tid];
#pragma unroll
    for (int i = 1; i < 16; ++i) {
      float4 r = red[i][tid];
      w.x += r.x; w.y += r.y; w.z += r.z; w.w += r.w;
    }
    ((float4*)(out_window + (size_t)b * A_SZ))[tid] = w;
  }
}

extern "C" void kernel_launch(void* const* d_in, const int* in_sizes, int n_in,
                              void* d_out, int out_size, void* d_ws, size_t ws_size,
                              hipStream_t stream) {
  const float* x    = (const float*)d_in[0];
  const float* text = (const float*)d_in[1];
  const float* pk   = (const float*)d_in[2];
  const float* Wa   = (const float*)d_in[3];
  const float* ba   = (const float*)d_in[4];
  const float* Wb   = (const float*)d_in[5];
  const float* bb   = (const float*)d_in[6];
  const float* Wk   = (const float*)d_in[7];
  const float* bk   = (const float*)d_in[8];

  float* out        = (float*)d_out;
  float* out_phi    = out;                              // B*C
  float* out_kappa  = out + (size_t)B_SZ * C_SZ;        // B*K
  float* out_win    = out_kappa + (size_t)B_SZ * K_SZ;  // B*A

  float* ws         = (float*)d_ws;
  float* ws_alpha   = ws;
  float* ws_beta    = ws + (size_t)B_SZ * K_SZ;
  float* ws_kappa   = ws + (size_t)2 * B_SZ * K_SZ;

  gw_abk<<<B_SZ / 2, 768, 0, stream>>>(x, pk, Wa, ba, Wb, bb, Wk, bk,
                                       ws_alpha, ws_beta, ws_kappa, out_kappa);
  gw_phi_window<<<B_SZ, 512, 0, stream>>>(text, ws_alpha, ws_beta, ws_kappa,
                                          out_phi, out_win);
}